// Round 6
// baseline (251.908 us; speedup 1.0000x reference)
//
#include <hip/hip_runtime.h>
#include <hip/hip_bf16.h>
#include <stdint.h>

#define N_BATCH 16384
#define D_IN    2048
#define E_OUT   512
#define K_CONV  1537   // D_IN - E_OUT + 1
#define EPS_N   1e-12f
#define BKD     32     // K-depth per step (one MFMA-K)
#define NSTEP   64     // k-steps over full [0, 2048)
#define ACT2    50     // active steps per 64-col quadrant (band union = 1600 k)

typedef unsigned short u16;
typedef __bf16 bf16x8 __attribute__((ext_vector_type(8)));
typedef float  f32x4  __attribute__((ext_vector_type(4)));

__device__ __forceinline__ unsigned f2bf_sw(float f) {
    union { float f; unsigned int u; } a; a.f = f;
    unsigned int r = a.u + 0x7FFFu + ((a.u >> 16) & 1u);   // RNE
    return r >> 16;
}

__device__ __forceinline__ unsigned pk_bf16(float a, float b) {
#if __has_builtin(__builtin_amdgcn_cvt_pk_bf16_f32)
    typedef __bf16 bf16x2 __attribute__((ext_vector_type(2)));
    bf16x2 r = __builtin_amdgcn_cvt_pk_bf16_f32(a, b);     // HW RNE, 1 inst / 2 elems
    union { bf16x2 v; unsigned u; } c; c.v = r;
    return c.u;
#else
    return f2bf_sw(a) | (f2bf_sw(b) << 16);
#endif
}

// ---------------- densify banded W into bf16 (E_OUT x D_IN) ----------------
__global__ __launch_bounds__(256) void prep_w_kernel(const float* __restrict__ w,
                                                     u16* __restrict__ wb) {
    int idx = blockIdx.x * 256 + threadIdx.x;
    int e = idx >> 11;
    int d = idx & (D_IN - 1);
    int k = d - e;
    float v = (k >= 0 && k < K_CONV) ? w[e * K_CONV + k] : 0.0f;
    wb[idx] = (u16)f2bf_sw(v);
}

// ---------------- ONE fused kernel: GEMM + bias + normalize + store ----------
// R4 diagnosis: 2-stage pipeline exposes (staging latency - 1 step) at every
// barrier (MfmaUtil 11%, nothing saturated, 1 block/CU -> no co-resident cover).
// This version: 4-slot LDS ring at BKD=32, B staged 3 steps ahead, A regs 2
// ahead. Same LDS total (144 KB), same layout/fragments/epilogue/numerics.
// Issue order per step = [A-load, 4 B-glds]; barrier's counted vmcnt(9)
// (outstanding = B(t+2)x4 + A(t+2) + B(t+3)x4 = 9) drains exactly the tile
// aged 2+ steps (~800+ cyc cover), never the fresh prefetches.
// Bank-conflict note: every wave LDS access (frag reads, staging writes)
// tiles a contiguous aligned 1KB/512B region exactly once -> same bank-touch
// multiset as the canonical conflict-free lane-contiguous pattern; no swizzle.
__global__ __launch_bounds__(512, 2) void fused_kernel(const float* __restrict__ A,
                                                       const u16* __restrict__ B,
                                                       const float* __restrict__ bias,
                                                       float* __restrict__ out) {
    __shared__ __align__(16) u16 Asb[4][64][32];    // 16 KB  (A k-step ring)
    __shared__ __align__(16) u16 Bsb[4][512][32];   // 128 KB (full-E B k-step ring)
    __shared__ float ssq_lds[64];

    const int tid  = threadIdx.x;
    const int lane = tid & 63;
    const int wq   = tid >> 6;        // wave = n-quadrant (cols [64*wq, 64*wq+64))
    const int quad = lane >> 4;
    const int r16  = lane & 15;

    const int m0 = blockIdx.x * 64;

    // ---- A staging: thread -> 1 f32x4 chunk (row = tid>>3, c8 = tid&7) ----
    const float* agA = A + (size_t)(m0 + (tid >> 3)) * D_IN + (tid & 7) * 4;
    u16* asW = &Asb[0][0][0] + tid * 4;            // byte = tid*8, linear

    // ---- B staging (glds): 2048 chunks/step, 4/thread; lane-linear dest ----
    const u16* bg[4];
    u16* bsD[4];
#pragma unroll
    for (int c = 0; c < 4; ++c) {
        const int li = tid + 512 * c;
        const int e  = li >> 2;        // [0, 512)
        const int oc = li & 3;         // 16B chunk within 64B row
        bg[c]  = B + (size_t)e * D_IN + oc * 8;
        bsD[c] = &Bsb[0][0][0] + li * 8;
    }

    // ---- fragment read bases (u16 units); +i*512 walks 16-row frags ----
    const u16* aFb = &Asb[0][0][0] + r16 * 32 + quad * 8;
    const u16* bFb = &Bsb[0][0][0] + (wq * 64 + r16) * 32 + quad * 8;

    f32x4 acc[4][4] = {};
    f32x4 arE, arO;                    // A reg slots: step parity even / odd

#define LOAD_AF(dst)                                            \
    dst = *(const f32x4*)agA;                                   \
    agA += BKD;

#define PACK_A(src, buf)                                        \
    {                                                           \
        uint2 o;                                                \
        o.x = pk_bf16(src[0], src[1]);                          \
        o.y = pk_bf16(src[2], src[3]);                          \
        *(uint2*)(asW + (buf) * 2048) = o;                      \
    }

#define GLDS_B(buf)                                             \
    _Pragma("unroll")                                           \
    for (int c = 0; c < 4; ++c)                                 \
        __builtin_amdgcn_global_load_lds(                       \
            (const __attribute__((address_space(1))) void*)bg[c], \
            (__attribute__((address_space(3))) void*)(bsD[c] + (buf) * 16384), 16, 0, 0); \
    _Pragma("unroll")                                           \
    for (int c = 0; c < 4; ++c) bg[c] += BKD;

#define COMPUTE(buf, t)                                         \
    if ((t) >= 2 * wq && (t) < 2 * wq + ACT2) {                 \
        bf16x8 af[4], bf[4];                                    \
        _Pragma("unroll")                                       \
        for (int i = 0; i < 4; ++i)                             \
            af[i] = *(const bf16x8*)(aFb + (buf) * 2048 + i * 512); \
        _Pragma("unroll")                                       \
        for (int j = 0; j < 4; ++j)                             \
            bf[j] = *(const bf16x8*)(bFb + (buf) * 16384 + j * 512); \
        _Pragma("unroll")                                       \
        for (int i = 0; i < 4; ++i)                             \
            _Pragma("unroll")                                   \
            for (int j = 0; j < 4; ++j)                         \
                acc[i][j] = __builtin_amdgcn_mfma_f32_16x16x32_bf16(af[i], bf[j], acc[i][j], 0, 0, 0); \
    }

// steady-state barrier: vmcnt(9) = keep {B(t+2) x4, A(t+2), B(t+3) x4} in
// flight; forces everything older (incl. B(t+1), needed next step) to drain.
#define BAR_FAST()                                              \
    __builtin_amdgcn_sched_barrier(0);                          \
    asm volatile("s_waitcnt vmcnt(9) lgkmcnt(0)");              \
    __builtin_amdgcn_sched_barrier(0);                          \
    __builtin_amdgcn_s_barrier();                               \
    __builtin_amdgcn_sched_barrier(0);

// one pipeline step: compute tile t from ring slot t&3; A-load tile t+2 (issued
// FIRST so it is the oldest VMEM of this step); B-glds tile t+3 into slot
// (t+3)&3; pack tile t+1's A (regs loaded 1 step ago, drained by reg-dep wait).
#define STEP(t, LDSLOT, PKSLOT)                                 \
    {                                                           \
        LOAD_AF(LDSLOT);                                        \
        GLDS_B(((t) + 3) & 3);                                  \
        PACK_A(PKSLOT, ((t) + 1) & 3);                          \
        COMPUTE((t) & 3, (t));                                  \
        BAR_FAST();                                             \
    }

    // ---- prologue: stage B tiles 0,1,2; load A tiles 0,1; pack A0 ----
    {
        f32x4 arT;
        LOAD_AF(arT);                  // A tile 0
        LOAD_AF(arO);                  // A tile 1
        GLDS_B(0);                     // B tile 0
        GLDS_B(1);                     // B tile 1
        GLDS_B(2);                     // B tile 2
        PACK_A(arT, 0);               // one-time stall on A0 regs
        __syncthreads();               // full drain
    }

    // ---- main loop: 15 x 4 steps, t = 0..59 ----
    for (int u = 0; u < 15; ++u) {
        const int t0 = 4 * u;
        STEP(t0 + 0, arE, arO);
        STEP(t0 + 1, arO, arE);
        STEP(t0 + 2, arE, arO);
        STEP(t0 + 3, arO, arE);
    }

    // ---- peeled tail: t = 60..63 ----
    STEP(60, arE, arO);                // steady-state pattern (issues B63, A62)
    {                                  // t = 61: no more B to stage
        LOAD_AF(arO);                  // A tile 63
        PACK_A(arE, 62 & 3);           // A tile 62
        COMPUTE(61 & 3, 61);
        __syncthreads();               // full drain (tail - correctness first)
    }
    {                                  // t = 62
        PACK_A(arO, 63 & 3);           // A tile 63
        COMPUTE(62 & 3, 62);
        __syncthreads();
    }
    COMPUTE(63 & 3, 63);               // t = 63

    // ---- fused epilogue: bias, row-ssq reduce, normalize, single store ----
    __syncthreads();
    if (tid < 64) ssq_lds[tid] = 0.0f;

    float bv[4];
#pragma unroll
    for (int j = 0; j < 4; ++j) bv[j] = bias[wq * 64 + j * 16 + r16];

    __syncthreads();

    float ssq_t[16];
#pragma unroll
    for (int t = 0; t < 16; ++t) ssq_t[t] = 0.0f;

#pragma unroll
    for (int j = 0; j < 4; ++j)
#pragma unroll
        for (int i = 0; i < 4; ++i)
#pragma unroll
            for (int rg = 0; rg < 4; ++rg) {
                const float v = acc[i][j][rg] + bv[j];
                acc[i][j][rg] = v;
                ssq_t[i * 4 + rg] += v * v;
            }

#pragma unroll
    for (int off = 1; off <= 8; off <<= 1)
#pragma unroll
        for (int t = 0; t < 16; ++t)
            ssq_t[t] += __shfl_xor(ssq_t[t], off, 64);

    if (r16 == 0) {
#pragma unroll
        for (int i = 0; i < 4; ++i)
#pragma unroll
            for (int rg = 0; rg < 4; ++rg)
                atomicAdd(&ssq_lds[i * 16 + quad * 4 + rg], ssq_t[i * 4 + rg]);
    }
    __syncthreads();
    if (tid < 64) ssq_lds[tid] = 1.0f / fmaxf(sqrtf(ssq_lds[tid]), EPS_N);
    __syncthreads();

#pragma unroll
    for (int i = 0; i < 4; ++i)
#pragma unroll
        for (int rg = 0; rg < 4; ++rg) {
            const int rl = i * 16 + quad * 4 + rg;
            const float inv = ssq_lds[rl];
            float* orow = out + (size_t)(m0 + rl) * E_OUT + wq * 64 + r16;
#pragma unroll
            for (int j = 0; j < 4; ++j)
                orow[j * 16] = acc[i][j][rg] * inv;
        }
}

// ---------------- fallback: fused naive fp32 (only if ws too small) ----------------
__global__ __launch_bounds__(256) void naive_kernel(const float* __restrict__ x,
                                                    const float* __restrict__ w,
                                                    const float* __restrict__ b,
                                                    float* __restrict__ out) {
    __shared__ float xs[D_IN];
    __shared__ float os[E_OUT];
    __shared__ float red[4];
    const int n = blockIdx.x;
    const float* xr = x + (size_t)n * D_IN;
    for (int i = threadIdx.x; i < D_IN; i += 256) xs[i] = xr[i];
    __syncthreads();
    for (int i = threadIdx.x; i < E_OUT; i += 256) {
        float s = b[i];
        const float* wr = w + (size_t)i * K_CONV;
        for (int k = 0; k < K_CONV; ++k) s += wr[k] * xs[i + k];
        os[i] = s;
    }
    __syncthreads();
    float ss = 0.0f;
    for (int i = threadIdx.x; i < E_OUT; i += 256) ss += os[i] * os[i];
#pragma unroll
    for (int off = 32; off > 0; off >>= 1) ss += __shfl_xor(ss, off, 64);
    if ((threadIdx.x & 63) == 0) red[threadIdx.x >> 6] = ss;
    __syncthreads();
    const float inv = 1.0f / fmaxf(sqrtf(red[0] + red[1] + red[2] + red[3]), EPS_N);
    float* orow = out + (size_t)n * E_OUT;
    for (int i = threadIdx.x; i < E_OUT; i += 256) orow[i] = os[i] * inv;
}

extern "C" void kernel_launch(void* const* d_in, const int* in_sizes, int n_in,
                              void* d_out, int out_size, void* d_ws, size_t ws_size,
                              hipStream_t stream) {
    const float* x = (const float*)d_in[0];
    const float* w = (const float*)d_in[1];
    const float* b = (const float*)d_in[2];
    float* out = (float*)d_out;

    const size_t wb_bytes = (size_t)E_OUT * D_IN * sizeof(u16);   // 2 MiB

    if (ws_size < wb_bytes) {
        naive_kernel<<<N_BATCH, 256, 0, stream>>>(x, w, b, out);
        return;
    }

    u16* wb = (u16*)d_ws;

    prep_w_kernel<<<(E_OUT * D_IN) / 256, 256, 0, stream>>>(w, wb);

    fused_kernel<<<N_BATCH / 64, 512, 0, stream>>>(x, wb, b, out);
}

// Round 7
// 250.159 us; speedup vs baseline: 1.0070x; 1.0070x over previous
//
#include <hip/hip_runtime.h>
#include <hip/hip_bf16.h>
#include <stdint.h>

#define N_BATCH 16384
#define D_IN    2048
#define E_OUT   512
#define K_CONV  1537   // D_IN - E_OUT + 1
#define EPS_N   1e-12f
#define BKD     32     // K-depth per step (one MFMA-K)
#define NSTEP   64     // k-steps over full [0, 2048)
#define ACT2    50     // active steps per 64-col quadrant (band union = 1600 k)

typedef unsigned short u16;
typedef __bf16 bf16x8 __attribute__((ext_vector_type(8)));
typedef float  f32x4  __attribute__((ext_vector_type(4)));

__device__ __forceinline__ unsigned f2bf_sw(float f) {
    union { float f; unsigned int u; } a; a.f = f;
    unsigned int r = a.u + 0x7FFFu + ((a.u >> 16) & 1u);   // RNE
    return r >> 16;
}

__device__ __forceinline__ unsigned pk_bf16(float a, float b) {
#if __has_builtin(__builtin_amdgcn_cvt_pk_bf16_f32)
    typedef __bf16 bf16x2 __attribute__((ext_vector_type(2)));
    bf16x2 r = __builtin_amdgcn_cvt_pk_bf16_f32(a, b);     // HW RNE, 1 inst / 2 elems
    union { bf16x2 v; unsigned u; } c; c.v = r;
    return c.u;
#else
    return f2bf_sw(a) | (f2bf_sw(b) << 16);
#endif
}

// ---------------- densify banded W into bf16 (E_OUT x D_IN) ----------------
__global__ __launch_bounds__(256) void prep_w_kernel(const float* __restrict__ w,
                                                     u16* __restrict__ wb) {
    int idx = blockIdx.x * 256 + threadIdx.x;
    int e = idx >> 11;
    int d = idx & (D_IN - 1);
    int k = d - e;
    float v = (k >= 0 && k < K_CONV) ? w[e * K_CONV + k] : 0.0f;
    wb[idx] = (u16)f2bf_sw(v);
}

// ---------------- ONE fused kernel: GEMM + bias + normalize + store ----------
// R6 post-mortem: BKD=32 (64B LDS rows) made every ds_read_b128 fragment read
// a 4-way bank conflict (SQ_LDS_BANK_CONFLICT 0 -> 3.28M): conflict-freedom
// requires each consecutive-8-lane phase group to have distinct (byte>>4)&7,
// and at 64B rows lanes 0..7 give {0,4,0,4,...}. THIS round keeps the 4-slot
// ring + counted vmcnt(9) and adds:
//  (1) chunk swizzle p = l ^ s(row), s(row)=(row>>1)&3, applied at the A-pack
//      ds_write, at both fragment-read bases, and via PRE-SWIZZLED global
//      source for the B glds (lane-linear dest preserved; the permutation
//      stays inside each row's 64B segment -> coalescing unchanged).
//      Paper-verified: all 8-lane read groups hit 8 distinct 16B slots; all
//      16-lane b64 write phases tile 128B. -> conflicts ~0.
//  (2) T5 s_setprio(1) around the MFMA cluster (phase-split + counted-vmcnt
//      schedule is the regime where it measured +21-39%).
__global__ __launch_bounds__(512, 2) void fused_kernel(const float* __restrict__ A,
                                                       const u16* __restrict__ B,
                                                       const float* __restrict__ bias,
                                                       float* __restrict__ out) {
    __shared__ __align__(16) u16 Asb[4][64][32];    // 16 KB  (A k-step ring)
    __shared__ __align__(16) u16 Bsb[4][512][32];   // 128 KB (full-E B k-step ring)
    __shared__ float ssq_lds[64];

    const int tid  = threadIdx.x;
    const int lane = tid & 63;
    const int wq   = tid >> 6;        // wave = n-quadrant (cols [64*wq, 64*wq+64))
    const int quad = lane >> 4;
    const int r16  = lane & 15;

    const int m0 = blockIdx.x * 64;

    // ---- A staging: thread -> 1 f32x4 chunk (row = tid>>3, c8 = tid&7);
    //      logical chunk l = c8>>1, half h = c8&1; physical p = l ^ s(row)
    const float* agA = A + (size_t)(m0 + (tid >> 3)) * D_IN + (tid & 7) * 4;
    u16* asW;
    {
        const int row = tid >> 3;
        const int c8  = tid & 7;
        const int p   = (c8 >> 1) ^ ((row >> 1) & 3);
        asW = &Asb[0][0][0] + row * 32 + p * 8 + (c8 & 1) * 4;
    }

    // ---- B staging (glds): 2048 chunks/step, 4/thread; lane-linear dest,
    //      PRE-SWIZZLED source chunk (oc ^ s(e)) ----
    const u16* bg[4];
    u16* bsD[4];
#pragma unroll
    for (int c = 0; c < 4; ++c) {
        const int li = tid + 512 * c;
        const int e  = li >> 2;        // [0, 512)
        const int oc = li & 3;         // physical 16B chunk within 64B row
        const int sl = oc ^ ((e >> 1) & 3);   // logical chunk stored here
        bg[c]  = B + (size_t)e * D_IN + sl * 8;
        bsD[c] = &Bsb[0][0][0] + li * 8;
    }

    // ---- fragment read bases (u16 units), swizzled; +i*512 walks 16-row
    //      frags (row += 16 leaves s(row) unchanged) ----
    const int sw4 = (r16 >> 1) & 3;
    const u16* aFb = &Asb[0][0][0] + r16 * 32 + (quad ^ sw4) * 8;
    const u16* bFb = &Bsb[0][0][0] + (wq * 64 + r16) * 32 + (quad ^ sw4) * 8;

    f32x4 acc[4][4] = {};
    f32x4 arE, arO;                    // A reg slots: step parity even / odd

#define LOAD_AF(dst)                                            \
    dst = *(const f32x4*)agA;                                   \
    agA += BKD;

#define PACK_A(src, buf)                                        \
    {                                                           \
        uint2 o;                                                \
        o.x = pk_bf16(src[0], src[1]);                          \
        o.y = pk_bf16(src[2], src[3]);                          \
        *(uint2*)(asW + (buf) * 2048) = o;                      \
    }

#define GLDS_B(buf)                                             \
    _Pragma("unroll")                                           \
    for (int c = 0; c < 4; ++c)                                 \
        __builtin_amdgcn_global_load_lds(                       \
            (const __attribute__((address_space(1))) void*)bg[c], \
            (__attribute__((address_space(3))) void*)(bsD[c] + (buf) * 16384), 16, 0, 0); \
    _Pragma("unroll")                                           \
    for (int c = 0; c < 4; ++c) bg[c] += BKD;

#define COMPUTE(buf, t)                                         \
    if ((t) >= 2 * wq && (t) < 2 * wq + ACT2) {                 \
        bf16x8 af[4], bf[4];                                    \
        _Pragma("unroll")                                       \
        for (int i = 0; i < 4; ++i)                             \
            af[i] = *(const bf16x8*)(aFb + (buf) * 2048 + i * 512); \
        _Pragma("unroll")                                       \
        for (int j = 0; j < 4; ++j)                             \
            bf[j] = *(const bf16x8*)(bFb + (buf) * 16384 + j * 512); \
        __builtin_amdgcn_s_setprio(1);                          \
        _Pragma("unroll")                                       \
        for (int i = 0; i < 4; ++i)                             \
            _Pragma("unroll")                                   \
            for (int j = 0; j < 4; ++j)                         \
                acc[i][j] = __builtin_amdgcn_mfma_f32_16x16x32_bf16(af[i], bf[j], acc[i][j], 0, 0, 0); \
        __builtin_amdgcn_s_setprio(0);                          \
    }

// steady-state barrier: vmcnt(9) = keep {B(t+2) x4, A(t+2), B(t+3) x4} in
// flight; forces everything older (incl. B(t+1), needed next step) to drain.
#define BAR_FAST()                                              \
    __builtin_amdgcn_sched_barrier(0);                          \
    asm volatile("s_waitcnt vmcnt(9) lgkmcnt(0)");              \
    __builtin_amdgcn_sched_barrier(0);                          \
    __builtin_amdgcn_s_barrier();                               \
    __builtin_amdgcn_sched_barrier(0);

// one pipeline step: compute tile t from ring slot t&3; A-load tile t+2 (issued
// FIRST so it is the oldest VMEM of this step); B-glds tile t+3 into slot
// (t+3)&3; pack tile t+1's A (regs loaded 1 step ago, drained by reg-dep wait).
#define STEP(t, LDSLOT, PKSLOT)                                 \
    {                                                           \
        LOAD_AF(LDSLOT);                                        \
        GLDS_B(((t) + 3) & 3);                                  \
        PACK_A(PKSLOT, ((t) + 1) & 3);                          \
        COMPUTE((t) & 3, (t));                                  \
        BAR_FAST();                                             \
    }

    // ---- prologue: stage B tiles 0,1,2; load A tiles 0,1; pack A0 ----
    {
        f32x4 arT;
        LOAD_AF(arT);                  // A tile 0
        LOAD_AF(arO);                  // A tile 1
        GLDS_B(0);                     // B tile 0
        GLDS_B(1);                     // B tile 1
        GLDS_B(2);                     // B tile 2
        PACK_A(arT, 0);               // one-time stall on A0 regs
        __syncthreads();               // full drain
    }

    // ---- main loop: 15 x 4 steps, t = 0..59 ----
    for (int u = 0; u < 15; ++u) {
        const int t0 = 4 * u;
        STEP(t0 + 0, arE, arO);
        STEP(t0 + 1, arO, arE);
        STEP(t0 + 2, arE, arO);
        STEP(t0 + 3, arO, arE);
    }

    // ---- peeled tail: t = 60..63 ----
    STEP(60, arE, arO);                // steady-state pattern (issues B63, A62)
    {                                  // t = 61: no more B to stage
        LOAD_AF(arO);                  // A tile 63
        PACK_A(arE, 62 & 3);           // A tile 62
        COMPUTE(61 & 3, 61);
        __syncthreads();               // full drain (tail - correctness first)
    }
    {                                  // t = 62
        PACK_A(arO, 63 & 3);           // A tile 63
        COMPUTE(62 & 3, 62);
        __syncthreads();
    }
    COMPUTE(63 & 3, 63);               // t = 63

    // ---- fused epilogue: bias, row-ssq reduce, normalize, single store ----
    __syncthreads();
    if (tid < 64) ssq_lds[tid] = 0.0f;

    float bv[4];
#pragma unroll
    for (int j = 0; j < 4; ++j) bv[j] = bias[wq * 64 + j * 16 + r16];

    __syncthreads();

    float ssq_t[16];
#pragma unroll
    for (int t = 0; t < 16; ++t) ssq_t[t] = 0.0f;

#pragma unroll
    for (int j = 0; j < 4; ++j)
#pragma unroll
        for (int i = 0; i < 4; ++i)
#pragma unroll
            for (int rg = 0; rg < 4; ++rg) {
                const float v = acc[i][j][rg] + bv[j];
                acc[i][j][rg] = v;
                ssq_t[i * 4 + rg] += v * v;
            }

#pragma unroll
    for (int off = 1; off <= 8; off <<= 1)
#pragma unroll
        for (int t = 0; t < 16; ++t)
            ssq_t[t] += __shfl_xor(ssq_t[t], off, 64);

    if (r16 == 0) {
#pragma unroll
        for (int i = 0; i < 4; ++i)
#pragma unroll
            for (int rg = 0; rg < 4; ++rg)
                atomicAdd(&ssq_lds[i * 16 + quad * 4 + rg], ssq_t[i * 4 + rg]);
    }
    __syncthreads();
    if (tid < 64) ssq_lds[tid] = 1.0f / fmaxf(sqrtf(ssq_lds[tid]), EPS_N);
    __syncthreads();

#pragma unroll
    for (int i = 0; i < 4; ++i)
#pragma unroll
        for (int rg = 0; rg < 4; ++rg) {
            const int rl = i * 16 + quad * 4 + rg;
            const float inv = ssq_lds[rl];
            float* orow = out + (size_t)(m0 + rl) * E_OUT + wq * 64 + r16;
#pragma unroll
            for (int j = 0; j < 4; ++j)
                orow[j * 16] = acc[i][j][rg] * inv;
        }
}

// ---------------- fallback: fused naive fp32 (only if ws too small) ----------------
__global__ __launch_bounds__(256) void naive_kernel(const float* __restrict__ x,
                                                    const float* __restrict__ w,
                                                    const float* __restrict__ b,
                                                    float* __restrict__ out) {
    __shared__ float xs[D_IN];
    __shared__ float os[E_OUT];
    __shared__ float red[4];
    const int n = blockIdx.x;
    const float* xr = x + (size_t)n * D_IN;
    for (int i = threadIdx.x; i < D_IN; i += 256) xs[i] = xr[i];
    __syncthreads();
    for (int i = threadIdx.x; i < E_OUT; i += 256) {
        float s = b[i];
        const float* wr = w + (size_t)i * K_CONV;
        for (int k = 0; k < K_CONV; ++k) s += wr[k] * xs[i + k];
        os[i] = s;
    }
    __syncthreads();
    float ss = 0.0f;
    for (int i = threadIdx.x; i < E_OUT; i += 256) ss += os[i] * os[i];
#pragma unroll
    for (int off = 32; off > 0; off >>= 1) ss += __shfl_xor(ss, off, 64);
    if ((threadIdx.x & 63) == 0) red[threadIdx.x >> 6] = ss;
    __syncthreads();
    const float inv = 1.0f / fmaxf(sqrtf(red[0] + red[1] + red[2] + red[3]), EPS_N);
    float* orow = out + (size_t)n * E_OUT;
    for (int i = threadIdx.x; i < E_OUT; i += 256) orow[i] = os[i] * inv;
}

extern "C" void kernel_launch(void* const* d_in, const int* in_sizes, int n_in,
                              void* d_out, int out_size, void* d_ws, size_t ws_size,
                              hipStream_t stream) {
    const float* x = (const float*)d_in[0];
    const float* w = (const float*)d_in[1];
    const float* b = (const float*)d_in[2];
    float* out = (float*)d_out;

    const size_t wb_bytes = (size_t)E_OUT * D_IN * sizeof(u16);   // 2 MiB

    if (ws_size < wb_bytes) {
        naive_kernel<<<N_BATCH, 256, 0, stream>>>(x, w, b, out);
        return;
    }

    u16* wb = (u16*)d_ws;

    prep_w_kernel<<<(E_OUT * D_IN) / 256, 256, 0, stream>>>(w, wb);

    fused_kernel<<<N_BATCH / 64, 512, 0, stream>>>(x, wb, b, out);
}